// Round 14
// baseline (173.318 us; speedup 1.0000x reference)
//
#include <hip/hip_runtime.h>
#include <math.h>

#define N 4096
#define BSZ 2048
#define D 128
#define SH0 300000           // shadow region (floats); real data ends ~278560
#define SHS (SH0 + 4 * N)

typedef __bf16 bf16x8 __attribute__((ext_vector_type(8)));
typedef float f32x4 __attribute__((ext_vector_type(4)));
typedef unsigned short u16x8 __attribute__((ext_vector_type(8)));

__device__ __forceinline__ int rowbase(int i) {
    return (i & (BSZ - 1)) * (2 * D) + (i >> 11) * D;
}
__device__ __forceinline__ unsigned short f2bf(float x) {
    unsigned u = __float_as_uint(x);
    return (unsigned short)((u + 0x7fffu + ((u >> 16) & 1u)) >> 16);  // RNE
}

// ===================== real pipeline (R12 verbatim) =====================
__global__ void init_kernel(const float* __restrict__ feat, float* __restrict__ ws,
                            unsigned short* __restrict__ cf) {
    int t = threadIdx.x;
    int row = blockIdx.x * 16 + (t >> 4);
    int lq = t & 15;
    const float* p = feat + rowbase(row) + lq * 8;
    float4 v0 = *(const float4*)(p);
    float4 v1 = *(const float4*)(p + 4);
    float dot = v0.x * v0.x + v0.y * v0.y + v0.z * v0.z + v0.w * v0.w
              + v1.x * v1.x + v1.y * v1.y + v1.z * v1.z + v1.w * v1.w;
#pragma unroll
    for (int off = 1; off < 16; off <<= 1) dot += __shfl_xor(dot, off);

    u16x8 u;
    u[0] = f2bf(v0.x); u[1] = f2bf(v0.y); u[2] = f2bf(v0.z); u[3] = f2bf(v0.w);
    u[4] = f2bf(v1.x); u[5] = f2bf(v1.y); u[6] = f2bf(v1.z); u[7] = f2bf(v1.w);
    *(u16x8*)(cf + row * D + lq * 8) = u;

    if (lq == 0) {
        ws[row] = fminf(fmaxf(dot, -1.f), 1.f);
        ws[N + row] = 0.f;
        ws[2 * N + row] = 0.f;
        ws[3 * N + row] = 0.f;
    }
    if (blockIdx.x == 0 && t == 0) {
        ws[4 * N] = 0.f;
        ((unsigned int*)ws)[4 * N + 1] = 0u;
    }
}

__launch_bounds__(256)
__global__ void pair_kernel(const unsigned short* __restrict__ cf,
                            const int* __restrict__ labels, float* __restrict__ ws) {
    __shared__ unsigned short Abuf[128 * 64];
    __shared__ unsigned short Bbuf[128 * 64];
    __shared__ float labIf[128], labJf[128], mI[128];

    const int t = threadIdx.x;
    const int bi = blockIdx.x >> 5;
    const int bj = blockIdx.x & 31;
    const int i0 = bi * 128, j0 = bj * 128;

    if (t < 128) {
        labIf[t] = (float)labels[(i0 + t) & (BSZ - 1)];
        mI[t] = ws[i0 + t];
    } else {
        int u = t - 128;
        labJf[u] = (float)labels[(j0 + u) & (BSZ - 1)];
    }

    const int wid = t >> 6, lane = t & 63;
    const int wp = wid >> 1, wq = wid & 1;
    const int lrow = lane & 15;
    const int srow = t >> 3;
    const int scc = t & 7;

    f32x4 acc[4][4] = {};

#pragma unroll
    for (int p = 0; p < 2; ++p) {
        u16x8 ra[4], rb[4];
#pragma unroll
        for (int it = 0; it < 4; ++it) {
            int row = it * 32 + srow;
            ra[it] = *(const u16x8*)(cf + (size_t)(j0 + row) * D + p * 64 + scc * 8);
            rb[it] = *(const u16x8*)(cf + (size_t)(i0 + row) * D + p * 64 + scc * 8);
        }
        if (p) __syncthreads();
#pragma unroll
        for (int it = 0; it < 4; ++it) {
            int row = it * 32 + srow;
            int sl = scc ^ (row & 7);
            *(u16x8*)(Abuf + row * 64 + sl * 8) = ra[it];
            *(u16x8*)(Bbuf + row * 64 + sl * 8) = rb[it];
        }
        __syncthreads();

#pragma unroll
        for (int k2 = 0; k2 < 2; ++k2) {
            const int ccf = k2 * 4 + (lane >> 4);
            const int sa = (ccf ^ (lrow & 7)) * 8;
            bf16x8 a[4], b[4];
#pragma unroll
            for (int r = 0; r < 4; ++r)
                a[r] = *(const bf16x8*)(Abuf + (wq * 64 + r * 16 + lrow) * 64 + sa);
#pragma unroll
            for (int c = 0; c < 4; ++c)
                b[c] = *(const bf16x8*)(Bbuf + (wp * 64 + c * 16 + lrow) * 64 + sa);
#pragma unroll
            for (int r = 0; r < 4; ++r)
#pragma unroll
                for (int c = 0; c < 4; ++c)
                    acc[r][c] = __builtin_amdgcn_mfma_f32_16x16x32_bf16(a[r], b[c], acc[r][c], 0, 0, 0);
        }
    }

    const int jbl = wq * 64 + ((lane >> 4) << 2);
    float lj[16];
#pragma unroll
    for (int ar = 0; ar < 4; ++ar)
#pragma unroll
        for (int rg = 0; rg < 4; ++rg)
            lj[ar * 4 + rg] = labJf[jbl + ar * 16 + rg];

    const bool hasDiag = (bi == bj);

#pragma unroll
    for (int ac = 0; ac < 4; ++ac) {
        const int ri = wp * 64 + ac * 16 + lrow;
        const int gi = i0 + ri;
        const float li = labIf[ri];
        const float m = mI[ri];
        const int dg = hasDiag ? (ri - jbl) : -1;
        float s1 = 0.f, sc = 0.f, ct = 0.f;
#pragma unroll
        for (int ar = 0; ar < 4; ++ar) {
#pragma unroll
            for (int rg = 0; rg < 4; ++rg) {
                float c = __builtin_amdgcn_fmed3f(acc[ar][ac][rg], -1.f, 1.f);
                float distf = li - lj[ar * 4 + rg];
                float rev = fmaf(distf, -0.005f, 0.5f);
                float cph = __builtin_amdgcn_cosf(rev);
                float sph = __builtin_fabsf(__builtin_amdgcn_sinf(rev));
                float st = __builtin_amdgcn_sqrtf(fmaf(-c, c, 1.000001f));
                float nl = fmaf(c, cph, -st * sph);
                bool pos = (distf == 0.f);
                bool diag = (dg == ar * 16 + rg);
                float logit = pos ? (c - m) : nl;
                float e = diag ? 0.f : __expf(logit);
                float pf = (pos && !diag) ? 1.f : 0.f;
                s1 += e;
                sc = fmaf(pf, c, sc);
                ct += pf;
            }
        }
        s1 += __shfl_xor(s1, 16); s1 += __shfl_xor(s1, 32);
        sc += __shfl_xor(sc, 16); sc += __shfl_xor(sc, 32);
        ct += __shfl_xor(ct, 16); ct += __shfl_xor(ct, 32);
        if (lane < 16) {
            atomicAdd(&ws[N + gi], s1);
            atomicAdd(&ws[2 * N + gi], sc);
            atomicAdd(&ws[3 * N + gi], ct);
        }
    }
}

__global__ void final_kernel(float* __restrict__ ws, float* __restrict__ out) {
    __shared__ float red[4];
    const int t = threadIdx.x;
    const int i = blockIdx.x * 256 + t;

    float ct = ws[3 * N + i];
    float lp = ws[2 * N + i] - ct * ws[i] - ct * __logf(ws[N + i]);
    float v = (lp + 1e-6f) / (ct + 1e-6f);
#pragma unroll
    for (int off = 1; off < 64; off <<= 1) v += __shfl_xor(v, off);
    if ((t & 63) == 0) red[t >> 6] = v;
    __syncthreads();

    if (t == 0) {
        float bsum = red[0] + red[1] + red[2] + red[3];
        atomicAdd(&ws[4 * N], bsum);
        __threadfence();
        unsigned int old = atomicAdd(&((unsigned int*)ws)[4 * N + 1], 1u);
        if (old == 15u) {
            float total = __hip_atomic_load(&ws[4 * N], __ATOMIC_ACQUIRE,
                                            __HIP_MEMORY_SCOPE_AGENT);
            out[0] = -total / (float)N;
        }
    }
}

// ============ probes: MODE 0 = full clone, 1 = stage+MFMA only, 2 = epilogue only ============
template <int MODE, int REPS>
__launch_bounds__(256)
__global__ void probe(const unsigned short* __restrict__ cf,
                      const int* __restrict__ labels, float* __restrict__ ws) {
    __shared__ unsigned short Abuf[128 * 64];
    __shared__ unsigned short Bbuf[128 * 64];
    __shared__ float labIf[128], labJf[128], mI[128];

    const int t = threadIdx.x;
    const int bi = blockIdx.x >> 5;
    const int bj = blockIdx.x & 31;
    const int i0 = bi * 128, j0 = bj * 128;

    if (t < 128) {
        labIf[t] = (float)labels[(i0 + t) & (BSZ - 1)];
        mI[t] = ws[i0 + t];
    } else {
        int u = t - 128;
        labJf[u] = (float)labels[(j0 + u) & (BSZ - 1)];
    }

    const int wid = t >> 6, lane = t & 63;
    const int wp = wid >> 1, wq = wid & 1;
    const int lrow = lane & 15;
    const int srow = t >> 3;
    const int scc = t & 7;

    f32x4 acc[4][4] = {};
    float sink = 0.f;

    for (int rep = 0; rep < REPS; ++rep) {
        int z = 0; asm volatile("" : "+v"(z));          // opaque 0 (ptr perturb)
        float zf = 0.f; asm volatile("" : "+v"(zf));    // opaque 0.f

        if (MODE <= 1) {
            // ---- staging + MFMA (R12 structure) ----
            __syncthreads();   // protect LDS across reps
#pragma unroll
            for (int p = 0; p < 2; ++p) {
                u16x8 ra[4], rb[4];
#pragma unroll
                for (int it = 0; it < 4; ++it) {
                    int row = it * 32 + srow;
                    ra[it] = *(const u16x8*)(cf + (size_t)(j0 + row) * D + p * 64 + scc * 8 + z);
                    rb[it] = *(const u16x8*)(cf + (size_t)(i0 + row) * D + p * 64 + scc * 8 + z);
                }
                if (p) __syncthreads();
#pragma unroll
                for (int it = 0; it < 4; ++it) {
                    int row = it * 32 + srow;
                    int sl = scc ^ (row & 7);
                    *(u16x8*)(Abuf + row * 64 + sl * 8) = ra[it];
                    *(u16x8*)(Bbuf + row * 64 + sl * 8) = rb[it];
                }
                __syncthreads();
#pragma unroll
                for (int k2 = 0; k2 < 2; ++k2) {
                    const int ccf = k2 * 4 + (lane >> 4);
                    const int sa = (ccf ^ (lrow & 7)) * 8;
                    bf16x8 a[4], b[4];
#pragma unroll
                    for (int r = 0; r < 4; ++r)
                        a[r] = *(const bf16x8*)(Abuf + (wq * 64 + r * 16 + lrow) * 64 + sa);
#pragma unroll
                    for (int c = 0; c < 4; ++c)
                        b[c] = *(const bf16x8*)(Bbuf + (wp * 64 + c * 16 + lrow) * 64 + sa);
#pragma unroll
                    for (int r = 0; r < 4; ++r)
#pragma unroll
                        for (int c = 0; c < 4; ++c)
                            acc[r][c] = __builtin_amdgcn_mfma_f32_16x16x32_bf16(a[r], b[c], acc[r][c], 0, 0, 0);
                }
            }
        }

        if (MODE != 1) {
            // ---- epilogue (R12 structure) ----
            const int jbl = wq * 64 + ((lane >> 4) << 2);
            float lj[16];
#pragma unroll
            for (int ar = 0; ar < 4; ++ar)
#pragma unroll
                for (int rg = 0; rg < 4; ++rg)
                    lj[ar * 4 + rg] = labJf[jbl + ar * 16 + rg];

            const bool hasDiag = (bi == bj);
#pragma unroll
            for (int ac = 0; ac < 4; ++ac) {
                const int ri = wp * 64 + ac * 16 + lrow;
                const int gi = i0 + ri;
                const float li = labIf[ri];
                const float m = mI[ri];
                const int dg = hasDiag ? (ri - jbl) : -1;
                float s1 = 0.f, sc = 0.f, ct = 0.f;
#pragma unroll
                for (int ar = 0; ar < 4; ++ar) {
#pragma unroll
                    for (int rg = 0; rg < 4; ++rg) {
                        float c = __builtin_amdgcn_fmed3f(acc[ar][ac][rg] + zf, -1.f, 1.f);
                        float distf = li - lj[ar * 4 + rg] + zf;
                        float rev = fmaf(distf, -0.005f, 0.5f);
                        float cph = __builtin_amdgcn_cosf(rev);
                        float sph = __builtin_fabsf(__builtin_amdgcn_sinf(rev));
                        float st = __builtin_amdgcn_sqrtf(fmaf(-c, c, 1.000001f));
                        float nl = fmaf(c, cph, -st * sph);
                        bool pos = (distf == 0.f);
                        bool diag = (dg == ar * 16 + rg);
                        float logit = pos ? (c - m) : nl;
                        float e = diag ? 0.f : __expf(logit);
                        float pf = (pos && !diag) ? 1.f : 0.f;
                        s1 += e;
                        sc = fmaf(pf, c, sc);
                        ct += pf;
                    }
                }
                s1 += __shfl_xor(s1, 16); s1 += __shfl_xor(s1, 32);
                sc += __shfl_xor(sc, 16); sc += __shfl_xor(sc, 32);
                ct += __shfl_xor(ct, 16); ct += __shfl_xor(ct, 32);
                if (lane < 16) {
                    atomicAdd(&ws[SH0 + gi], s1);
                    atomicAdd(&ws[SH0 + N + gi], sc + ct);
                }
            }
        }
    }

    if (MODE == 1) {
#pragma unroll
        for (int r = 0; r < 4; ++r)
#pragma unroll
            for (int c = 0; c < 4; ++c)
#pragma unroll
                for (int k = 0; k < 4; ++k) sink += acc[r][c][k];
        ws[SHS + blockIdx.x * 256 + t] = sink;
    }
}

extern "C" void kernel_launch(void* const* d_in, const int* in_sizes, int n_in,
                              void* d_out, int out_size, void* d_ws, size_t ws_size,
                              hipStream_t stream) {
    const float* feat = (const float*)d_in[0];
    const int* labels = (const int*)d_in[1];
    float* ws = (float*)d_ws;
    unsigned short* cf = (unsigned short*)((float*)d_ws + 4 * N + 16);
    float* out = (float*)d_out;

    init_kernel<<<N / 16, 256, 0, stream>>>(feat, ws, cf);
    pair_kernel<<<1024, 256, 0, stream>>>(cf, labels, ws);
    final_kernel<<<16, 256, 0, stream>>>(ws, out);

    // diagnostics (shadow writes only)
    probe<0, 3><<<1024, 256, 0, stream>>>(cf, labels, ws);
    probe<1, 6><<<1024, 256, 0, stream>>>(cf, labels, ws);
    probe<2, 8><<<1024, 256, 0, stream>>>(cf, labels, ws);
}

// Round 15
// 39.406 us; speedup vs baseline: 4.3983x; 4.3983x over previous
//
#include <hip/hip_runtime.h>
#include <math.h>

#define N 4096
#define BSZ 2048
#define D 128
#define NLAB 100

// float offsets in ws
#define OFF_M   0
#define OFF_S1  N
#define OFF_PC  (2 * N)
#define OFF_SC  (3 * N)
#define OFF_ACC (4 * N)
#define OFF_CNT (4 * N + 1)
// int offsets
#define IOFF_H  (4 * N + 8)      // hist[100]
#define IOFF_B  (4 * N + 128)    // bucket[100][64]
#define OFF_CF  (4 * N + 128 + NLAB * 64)   // = 22912 floats, 16B aligned

typedef __bf16 bf16x8 __attribute__((ext_vector_type(8)));
typedef float f32x4 __attribute__((ext_vector_type(4)));
typedef unsigned short u16x8 __attribute__((ext_vector_type(8)));

__device__ __forceinline__ int rowbase(int i) {
    return (i & (BSZ - 1)) * (2 * D) + (i >> 11) * D;
}
__device__ __forceinline__ unsigned short f2bf(float x) {
    unsigned u = __float_as_uint(x);
    return (unsigned short)((u + 0x7fffu + ((u >> 16) & 1u)) >> 16);  // RNE
}
__device__ __forceinline__ float bf2f(unsigned short u) {
    return __uint_as_float((unsigned)u << 16);
}

__global__ void init_kernel(const float* __restrict__ feat, float* __restrict__ ws,
                            unsigned short* __restrict__ cf) {
    int t = threadIdx.x;
    int row = blockIdx.x * 16 + (t >> 4);
    int lq = t & 15;
    const float* p = feat + rowbase(row) + lq * 8;
    float4 v0 = *(const float4*)(p);
    float4 v1 = *(const float4*)(p + 4);
    float dot = v0.x * v0.x + v0.y * v0.y + v0.z * v0.z + v0.w * v0.w
              + v1.x * v1.x + v1.y * v1.y + v1.z * v1.z + v1.w * v1.w;
#pragma unroll
    for (int off = 1; off < 16; off <<= 1) dot += __shfl_xor(dot, off);

    u16x8 u;
    u[0] = f2bf(v0.x); u[1] = f2bf(v0.y); u[2] = f2bf(v0.z); u[3] = f2bf(v0.w);
    u[4] = f2bf(v1.x); u[5] = f2bf(v1.y); u[6] = f2bf(v1.z); u[7] = f2bf(v1.w);
    *(u16x8*)(cf + row * D + lq * 8) = u;

    if (lq == 0) {
        ws[OFF_M + row] = fminf(fmaxf(dot, -1.f), 1.f);  // rowmax = clipped fp32 diag
        ws[OFF_S1 + row] = 0.f;
    }
    if (blockIdx.x == 0) {
        if (t < NLAB) ((int*)ws)[IOFF_H + t] = 0;
        if (t == 0) {
            ws[OFF_ACC] = 0.f;
            ((unsigned int*)ws)[OFF_CNT] = 0u;
        }
    }
}

// build label buckets: 8 blocks x 256 = 2048 items
__global__ void prep_kernel(const int* __restrict__ labels, float* __restrict__ ws) {
    int b = blockIdx.x * 256 + threadIdx.x;
    int lab = labels[b];
    int* histI = (int*)ws + IOFF_H;
    int* bucket = (int*)ws + IOFF_B;
    int slot = atomicAdd(&histI[lab], 1);
    if (slot < 64) bucket[lab * 64 + slot] = b;
}

// 1024 blocks x 256: 128x128 tiles; R12 staging+MFMA; uniform neg-only epilogue
__launch_bounds__(256)
__global__ void pair_kernel(const unsigned short* __restrict__ cf,
                            const int* __restrict__ labels, float* __restrict__ ws) {
    __shared__ unsigned short Abuf[128 * 64];
    __shared__ unsigned short Bbuf[128 * 64];
    __shared__ float2 tab[199];
    __shared__ int labI[128], labJ[128];

    const int t = threadIdx.x;
    const int bi = blockIdx.x >> 5;
    const int bj = blockIdx.x & 31;
    const int i0 = bi * 128, j0 = bj * 128;

    if (t < 199) {
        float rev = fmaf((float)(t - 99), -0.005f, 0.5f);   // phi in revolutions
        tab[t] = make_float2(__builtin_amdgcn_cosf(rev),
                             __builtin_fabsf(__builtin_amdgcn_sinf(rev)));
    }
    if (t < 128) labI[t] = labels[(i0 + t) & (BSZ - 1)];
    else         labJ[t - 128] = labels[(j0 + (t - 128)) & (BSZ - 1)];

    const int wid = t >> 6, lane = t & 63;
    const int wp = wid >> 1, wq = wid & 1;
    const int lrow = lane & 15;
    const int srow = t >> 3;
    const int scc = t & 7;

    f32x4 acc[4][4] = {};

#pragma unroll
    for (int p = 0; p < 2; ++p) {
        u16x8 ra[4], rb[4];
#pragma unroll
        for (int it = 0; it < 4; ++it) {
            int row = it * 32 + srow;
            ra[it] = *(const u16x8*)(cf + (size_t)(j0 + row) * D + p * 64 + scc * 8);
            rb[it] = *(const u16x8*)(cf + (size_t)(i0 + row) * D + p * 64 + scc * 8);
        }
        if (p) __syncthreads();
#pragma unroll
        for (int it = 0; it < 4; ++it) {
            int row = it * 32 + srow;
            int sl = scc ^ (row & 7);
            *(u16x8*)(Abuf + row * 64 + sl * 8) = ra[it];
            *(u16x8*)(Bbuf + row * 64 + sl * 8) = rb[it];
        }
        __syncthreads();

#pragma unroll
        for (int k2 = 0; k2 < 2; ++k2) {
            const int ccf = k2 * 4 + (lane >> 4);
            const int sa = (ccf ^ (lrow & 7)) * 8;
            bf16x8 a[4], b[4];
#pragma unroll
            for (int r = 0; r < 4; ++r)
                a[r] = *(const bf16x8*)(Abuf + (wq * 64 + r * 16 + lrow) * 64 + sa);
#pragma unroll
            for (int c = 0; c < 4; ++c)
                b[c] = *(const bf16x8*)(Bbuf + (wp * 64 + c * 16 + lrow) * 64 + sa);
#pragma unroll
            for (int r = 0; r < 4; ++r)
#pragma unroll
                for (int c = 0; c < 4; ++c)
                    acc[r][c] = __builtin_amdgcn_mfma_f32_16x16x32_bf16(a[r], b[c], acc[r][c], 0, 0, 0);
        }
    }

    // per-lane J labels: jr_local = wq*64 + ar*16 + (lane>>4)*4 + rg
    const int jbl = wq * 64 + ((lane >> 4) << 2);
    int ljI[16];
#pragma unroll
    for (int ar = 0; ar < 4; ++ar)
#pragma unroll
        for (int rg = 0; rg < 4; ++rg)
            ljI[ar * 4 + rg] = labJ[jbl + ar * 16 + rg];

    // uniform neg-path over ALL j (diag/positives corrected by sparse_kernel)
#pragma unroll
    for (int ac = 0; ac < 4; ++ac) {
        const int ri = wp * 64 + ac * 16 + lrow;
        const int gi = i0 + ri;
        const int liP99 = labI[ri] + 99;
        float s1 = 0.f;
#pragma unroll
        for (int ar = 0; ar < 4; ++ar) {
#pragma unroll
            for (int rg = 0; rg < 4; ++rg) {
                float c = __builtin_amdgcn_fmed3f(acc[ar][ac][rg], -1.f, 1.f);
                float2 cs = tab[liP99 - ljI[ar * 4 + rg]];
                float st = __builtin_amdgcn_sqrtf(fmaf(-c, c, 1.000001f));
                float nl = fmaf(c, cs.x, -st * cs.y);
                s1 += __expf(nl);
            }
        }
        s1 += __shfl_xor(s1, 16); s1 += __shfl_xor(s1, 32);
        if (lane < 16) atomicAdd(&ws[OFF_S1 + gi], s1);
    }
}

// 1024 blocks x 256 (4 waves): wave = one row i; lanes = positive anchors
__launch_bounds__(256)
__global__ void sparse_kernel(const unsigned short* __restrict__ cf,
                              const int* __restrict__ labels, float* __restrict__ ws) {
    const int t = threadIdx.x;
    const int wid = t >> 6, lane = t & 63;
    const int i = blockIdx.x * 4 + wid;

    const int lab = labels[i & (BSZ - 1)];
    const int* histI = (const int*)ws + IOFF_H;
    const int* bucket = (const int*)ws + IOFF_B;
    const int h = min(histI[lab], 64);
    const float m = ws[OFF_M + i];
    const unsigned short* ci = cf + (size_t)i * D;

    float pc = 0.f, scv = 0.f;
    for (int base = 0; base < 2 * h; base += 64) {
        int l = base + lane;
        if (l < 2 * h) {
            int b = bucket[lab * 64 + (l >> 1)];
            int j = ((l & 1) << 11) + b;
            const unsigned short* cj = cf + (size_t)j * D;
            float dot = 0.f;
#pragma unroll
            for (int k = 0; k < 16; ++k) {
                u16x8 A = *(const u16x8*)(ci + k * 8);
                u16x8 B = *(const u16x8*)(cj + k * 8);
#pragma unroll
                for (int e = 0; e < 8; ++e)
                    dot = fmaf(bf2f(A[e]), bf2f(B[e]), dot);
            }
            float c = __builtin_amdgcn_fmed3f(dot, -1.f, 1.f);
            float em = __expf(-c);            // exp(neg_logit) at dist=0
            if (j == i) {
                pc -= em;                     // remove diagonal's neg term
            } else {
                pc += __expf(c - m) - em;     // positive: swap neg -> logits
                scv += c;
            }
        }
    }
#pragma unroll
    for (int off = 1; off < 64; off <<= 1) {
        pc += __shfl_xor(pc, off);
        scv += __shfl_xor(scv, off);
    }
    if (lane == 0) {
        ws[OFF_PC + i] = pc;
        ws[OFF_SC + i] = scv;
    }
}

// 16 blocks x 256: one row per thread; last block writes the scalar out
__global__ void final_kernel(const int* __restrict__ labels,
                             float* __restrict__ ws, float* __restrict__ out) {
    __shared__ float red[4];
    const int t = threadIdx.x;
    const int i = blockIdx.x * 256 + t;

    const int lab = labels[i & (BSZ - 1)];
    const float ct = 2.f * (float)(((const int*)ws)[IOFF_H + lab]) - 1.f;
    const float S1 = ws[OFF_S1 + i] + ws[OFF_PC + i];
    float lp = ws[OFF_SC + i] - ct * ws[OFF_M + i] - ct * __logf(S1);
    float v = (lp + 1e-6f) / (ct + 1e-6f);
#pragma unroll
    for (int off = 1; off < 64; off <<= 1) v += __shfl_xor(v, off);
    if ((t & 63) == 0) red[t >> 6] = v;
    __syncthreads();

    if (t == 0) {
        float bsum = red[0] + red[1] + red[2] + red[3];
        atomicAdd(&ws[OFF_ACC], bsum);
        __threadfence();
        unsigned int old = atomicAdd(&((unsigned int*)ws)[OFF_CNT], 1u);
        if (old == 15u) {
            float total = __hip_atomic_load(&ws[OFF_ACC], __ATOMIC_ACQUIRE,
                                            __HIP_MEMORY_SCOPE_AGENT);
            out[0] = -total / (float)N;
        }
    }
}

extern "C" void kernel_launch(void* const* d_in, const int* in_sizes, int n_in,
                              void* d_out, int out_size, void* d_ws, size_t ws_size,
                              hipStream_t stream) {
    const float* feat = (const float*)d_in[0];
    const int* labels = (const int*)d_in[1];
    float* ws = (float*)d_ws;
    unsigned short* cf = (unsigned short*)(ws + OFF_CF);
    float* out = (float*)d_out;

    init_kernel<<<N / 16, 256, 0, stream>>>(feat, ws, cf);
    prep_kernel<<<BSZ / 256, 256, 0, stream>>>(labels, ws);
    pair_kernel<<<1024, 256, 0, stream>>>(cf, labels, ws);
    sparse_kernel<<<1024, 256, 0, stream>>>(cf, labels, ws);
    final_kernel<<<16, 256, 0, stream>>>(labels, ws, out);
}